// Round 6
// baseline (370.596 us; speedup 1.0000x reference)
//
#include <hip/hip_runtime.h>
#include <cmath>

#define DEV __device__ __forceinline__

typedef __attribute__((ext_vector_type(8))) unsigned short ushort8v;
typedef __attribute__((ext_vector_type(8))) short short8v;
typedef __attribute__((ext_vector_type(4))) float f32x4;

DEV float lrelu(float v) { return fmaxf(v, 0.2f * v); }
DEV float elu(float v) { return v > 0.f ? v : expm1f(v); }
DEV float bf2f(unsigned short u) { return __uint_as_float((unsigned)u << 16); }
DEV float plo(unsigned u) { return __uint_as_float(u << 16); }
DEV float phi(unsigned u) { return __uint_as_float(u & 0xffff0000u); }
DEV unsigned short f2bf(float f) {
  unsigned u = __float_as_uint(f);
  unsigned r = (u + 0x7fffu + ((u >> 16) & 1u)) >> 16;
  return (unsigned short)r;
}
DEV unsigned packbf(float a, float b) {
  return (unsigned)f2bf(a) | ((unsigned)f2bf(b) << 16);
}
DEV void unpack8(uint4 u, float* f) {
  f[0] = plo(u.x); f[1] = phi(u.x); f[2] = plo(u.y); f[3] = phi(u.y);
  f[4] = plo(u.z); f[5] = phi(u.z); f[6] = plo(u.w); f[7] = phi(u.w);
}

// ---------------- CSR build ----------------
__global__ void k_count(const int* __restrict__ ei, int* __restrict__ counts,
                        int E0, int ET) {
  int e = blockIdx.x * 256 + threadIdx.x;
  if (e >= ET) return;
  int dst = (e < E0) ? ei[E0 + e] : (e - E0);
  atomicAdd(&counts[dst], 1);
}

__global__ __launch_bounds__(1024) void k_scan2(const int* __restrict__ counts,
                                                int* __restrict__ offs, int n) {
  int t = threadIdx.x;
  int ch = (n + 1023) >> 10;
  int beg = t * ch, end = min(beg + ch, n);
  int loc = 0;
  for (int i = beg; i < end; ++i) loc += counts[i];
  int lane = t & 63, w = t >> 6;
  int v = loc;
#pragma unroll
  for (int m = 1; m < 64; m <<= 1) {
    int u = __shfl_up(v, m);
    if (lane >= m) v += u;
  }
  __shared__ int wsum[16], wpre[16];
  if (lane == 63) wsum[w] = v;
  __syncthreads();
  if (t < 16) {
    int p = 0;
    for (int i = 0; i < t; ++i) p += wsum[i];
    wpre[t] = p;
  }
  __syncthreads();
  int run = wpre[w] + v - loc;
  for (int i = beg; i < end; ++i) { offs[i] = run; run += counts[i]; }
  if (beg < n && end == n) offs[n] = run;
}

__global__ void k_scatter(const int* __restrict__ ei, const int* __restrict__ offs,
                          int* __restrict__ cursor, int* __restrict__ src_s,
                          int E0, int ET) {
  int e = blockIdx.x * 256 + threadIdx.x;
  if (e >= ET) return;
  int src, dst;
  if (e < E0) { src = ei[e]; dst = ei[E0 + e]; }
  else        { src = e - E0; dst = e - E0; }
  int pos = offs[dst] + atomicAdd(&cursor[dst], 1);
  src_s[pos] = src;
}

// ---------------- Weight pack into MFMA B-fragment order ----------------
DEV void pack_one(const float* __restrict__ W, unsigned short* __restrict__ Wp,
                  int K, int N, int idx) {
  if (idx >= K * N) return;
  int j = idx & 7, l = (idx >> 3) & 63, r = idx >> 9;
  int KB = K / 32;
  int tile = r / KB, kb = r - tile * KB;
  int k = kb * 32 + (l >> 4) * 8 + j;
  int col = tile * 16 + (l & 15);
  Wp[idx] = f2bf(W[(size_t)k * N + col]);
}

__global__ void k_pack_all(const float* w0, const float* w1, const float* w2,
                           const float* w3, const float* w4, const float* w5,
                           const float* w6, const float* w7,
                           unsigned short* p0, unsigned short* p1, unsigned short* p2,
                           unsigned short* p3, unsigned short* p4, unsigned short* p5,
                           unsigned short* p6, unsigned short* p7) {
  int idx = blockIdx.x * 256 + threadIdx.x;
  pack_one(w0, p0, 128, 128, idx);
  pack_one(w1, p1, 128, 512, idx);
  pack_one(w2, p2, 128, 512, idx);
  pack_one(w3, p3, 512, 128, idx);
  pack_one(w4, p4, 512, 128, idx);
  pack_one(w5, p5, 128, 128, idx);
  pack_one(w6, p6, 128, 128, idx);
  pack_one(w7, p7, 128, 128, idx);
}

// ---------------- MFMA GEMM: C[M,N] = act(A[M,K](bf16) @ W + bias), RT row-tiles ----------------
template<int K, int N, int RT, int ACT, bool OF32, bool OB16>
__global__ __launch_bounds__(256) void k_mfma(const unsigned short* __restrict__ A,
                                              const unsigned short* __restrict__ Wp,
                                              const float* __restrict__ bias,
                                              float* __restrict__ Cf,
                                              unsigned short* __restrict__ Cb) {
  constexpr int KB = K / 32;
  constexpr int TPW = N / 64;
  __shared__ short As[RT * KB * 64 * 8];
  int row0 = blockIdx.x * (16 * RT);
  int t = threadIdx.x, lane = t & 63, w = t >> 6;
  for (int idx = t; idx < RT * KB * 64; idx += 256) {
    int r = idx / (KB * 64), rem = idx - r * (KB * 64);
    int kb = rem >> 6, l = rem & 63;
    const short8v* sp = reinterpret_cast<const short8v*>(
        A + (size_t)(row0 + r * 16 + (l & 15)) * K + kb * 32 + (l >> 4) * 8);
    reinterpret_cast<short8v*>(As)[idx] = *sp;
  }
  __syncthreads();
  f32x4 acc[RT][TPW];
#pragma unroll
  for (int r = 0; r < RT; ++r)
#pragma unroll
    for (int j = 0; j < TPW; ++j) acc[r][j] = f32x4{0.f, 0.f, 0.f, 0.f};
  const short8v* Bp = reinterpret_cast<const short8v*>(Wp);
  for (int kb = 0; kb < KB; ++kb) {
    short8v a[RT];
#pragma unroll
    for (int r = 0; r < RT; ++r)
      a[r] = reinterpret_cast<const short8v*>(As)[(r * KB + kb) * 64 + lane];
#pragma unroll
    for (int j = 0; j < TPW; ++j) {
      int tile = w * TPW + j;
      short8v b = Bp[(tile * KB + kb) * 64 + lane];
#pragma unroll
      for (int r = 0; r < RT; ++r)
        acc[r][j] = __builtin_amdgcn_mfma_f32_16x16x32_bf16(a[r], b, acc[r][j], 0, 0, 0);
    }
  }
#pragma unroll
  for (int j = 0; j < TPW; ++j) {
    int col = (w * TPW + j) * 16 + (lane & 15);
    float bs = bias[col];
#pragma unroll
    for (int rt = 0; rt < RT; ++rt)
#pragma unroll
      for (int r = 0; r < 4; ++r) {
        int row = row0 + rt * 16 + (lane >> 4) * 4 + r;
        float v = acc[rt][j][r] + bs;
        if (ACT == 1) v = fmaxf(v, 0.f);
        if (OF32) Cf[(size_t)row * N + col] = v;
        if (OB16) Cb[(size_t)row * N + col] = f2bf(v);
      }
  }
}

// ---------------- LayerNorm (x -> bf16) ----------------
template<int C, int ACT, bool OUT16>
__global__ void k_ln(const float* in, void* out, const float* g, const float* b) {
  constexpr int T = (C < 256) ? C : 256;
  constexpr int EPT = C / T;
  int row = blockIdx.x, t = threadIdx.x;
  const float* ip = in + (size_t)row * C;
  float v[EPT];
  float s = 0.f, s2 = 0.f;
#pragma unroll
  for (int e = 0; e < EPT; ++e) { float xv = ip[t + e * T]; v[e] = xv; s += xv; s2 += xv * xv; }
#pragma unroll
  for (int m = 1; m <= 32; m <<= 1) { s += __shfl_xor(s, m); s2 += __shfl_xor(s2, m); }
  __shared__ float w1s[2], w2s[2];
  if (T > 64) {
    if ((t & 63) == 0) { w1s[t >> 6] = s; w2s[t >> 6] = s2; }
    __syncthreads();
    s = w1s[0] + w1s[1];
    s2 = w2s[0] + w2s[1];
  }
  float mu = s * (1.0f / C);
  float var = s2 * (1.0f / C) - mu * mu;
  float rs = rsqrtf(var + 1e-5f);
#pragma unroll
  for (int e = 0; e < EPT; ++e) {
    int c = t + e * T;
    float y = (v[e] - mu) * rs * g[c] + b[c];
    if (ACT == 1) y = fmaxf(y, 0.f);
    if (ACT == 2) y = elu(y);
    if (OUT16) ((unsigned short*)out)[(size_t)row * C + c] = f2bf(y);
    else       ((float*)out)[(size_t)row * C + c] = y;
  }
}

// ---------------- Fused GATv2 layer 1: group-per-edge, 8 ch/lane ----------------
// Block per dst node. Wave w = head w. 4 groups x 16 lanes; group g handles edge i+g;
// lane l16 holds channels l16*8..+7 of the head. Online softmax per group, butterfly merge.
__global__ __launch_bounds__(256) void k_gat1(const int* __restrict__ offs,
                                              const int* __restrict__ src_s,
                                              const uint4* __restrict__ xl4,  // [M][64]
                                              const uint4* __restrict__ xr4,
                                              const float* __restrict__ att,  // [512]
                                              const float* __restrict__ bg,
                                              const float* __restrict__ lg,
                                              const float* __restrict__ lb,
                                              uint4* __restrict__ out4) {     // [M][64]
  int n = blockIdx.x;
  int st = offs[n], en = offs[n + 1];
  int t = threadIdx.x, lane = t & 63, w = t >> 6;
  int g = lane >> 4, l16 = lane & 15;
  unsigned rowo = (unsigned)(w * 16 + l16);
  int cb = w * 128 + l16 * 8;
  uint4 ur = xr4[(unsigned)n * 64u + rowo];
  float xr[8];
  unpack8(ur, xr);
  float atv[8];
  {
    const float4* atp = reinterpret_cast<const float4*>(att + cb);
    float4 a0 = atp[0], a1 = atp[1];
    atv[0] = a0.x; atv[1] = a0.y; atv[2] = a0.z; atv[3] = a0.w;
    atv[4] = a1.x; atv[5] = a1.y; atv[6] = a1.z; atv[7] = a1.w;
  }
  float m = -3.0e38f, s = 0.f;
  float acc[8];
#pragma unroll
  for (int k = 0; k < 8; ++k) acc[k] = 0.f;
  for (int i = st; i < en; i += 4) {
    int e = i + g;
    int src = src_s[e < en ? e : en - 1];
    uint4 u = xl4[(unsigned)src * 64u + rowo];
    float xv[8];
    unpack8(u, xv);
    float p = 0.f;
#pragma unroll
    for (int k = 0; k < 8; ++k) {
      float sv = xv[k] + xr[k];
      p = fmaf(atv[k], lrelu(sv), p);
    }
    p += __shfl_xor(p, 1);
    p += __shfl_xor(p, 2);
    p += __shfl_xor(p, 4);
    p += __shfl_xor(p, 8);
    if (e >= en) p = -3.0e38f;
    float mn = fmaxf(m, p);
    float al = __expf(m - mn);
    float we = __expf(p - mn);
    s = s * al + we;
#pragma unroll
    for (int k = 0; k < 8; ++k) acc[k] = fmaf(acc[k], al, we * xv[k]);
    m = mn;
  }
  // merge the 4 groups (butterfly over xor 16, 32)
#pragma unroll
  for (int d = 16; d < 64; d <<= 1) {
    float mo = __shfl_xor(m, d), so = __shfl_xor(s, d);
    float ao[8];
#pragma unroll
    for (int k = 0; k < 8; ++k) ao[k] = __shfl_xor(acc[k], d);
    float mn = fmaxf(m, mo);
    float e1 = __expf(m - mn), e2 = __expf(mo - mn);
    s = s * e1 + so * e2;
#pragma unroll
    for (int k = 0; k < 8; ++k) acc[k] = acc[k] * e1 + ao[k] * e2;
    m = mn;
  }
  float inv = 1.0f / (s + 1e-16f);
  float v[8];
  float s1 = 0.f, s2 = 0.f;
#pragma unroll
  for (int k = 0; k < 8; ++k) {
    v[k] = fmaf(acc[k], inv, bg[cb + k]);
    s1 += v[k];
    s2 += v[k] * v[k];
  }
#pragma unroll
  for (int mm = 1; mm <= 32; mm <<= 1) { s1 += __shfl_xor(s1, mm); s2 += __shfl_xor(s2, mm); }
  __shared__ float r1[4], r2[4];
  if (lane == 0) { r1[w] = s1; r2[w] = s2; }
  __syncthreads();
  s1 = r1[0] + r1[1] + r1[2] + r1[3];
  s2 = r2[0] + r2[1] + r2[2] + r2[3];
  float mu = s1 * (1.0f / 2048.0f);              // each channel counted 4x (groups)
  float var = s2 * (1.0f / 2048.0f) - mu * mu;
  float rsd = rsqrtf(var + 1e-5f);
  if (g == 0) {
    float y[8];
#pragma unroll
    for (int k = 0; k < 8; ++k)
      y[k] = elu((v[k] - mu) * rsd * lg[cb + k] + lb[cb + k]);
    uint4 o;
    o.x = packbf(y[0], y[1]); o.y = packbf(y[2], y[3]);
    o.z = packbf(y[4], y[5]); o.w = packbf(y[6], y[7]);
    out4[(unsigned)n * 64u + rowo] = o;
  }
}

// ---------------- Fused GATv2 layer 2: wave per node, group-per-edge ----------------
__global__ __launch_bounds__(256) void k_gat2(const int* __restrict__ offs,
                                              const int* __restrict__ src_s,
                                              const uint4* __restrict__ xl4,  // [M][16]
                                              const uint4* __restrict__ xr4,
                                              const float* __restrict__ att,  // [128]
                                              const float* __restrict__ bg,
                                              const float* __restrict__ lg,
                                              const float* __restrict__ lb,
                                              float* __restrict__ emb,
                                              uint4* __restrict__ embh4,      // [M][16]
                                              int M) {
  int w = threadIdx.x >> 6, lane = threadIdx.x & 63;
  int n = blockIdx.x * 4 + w;
  if (n >= M) return;
  int st = offs[n], en = offs[n + 1];
  int g = lane >> 4, l16 = lane & 15;
  int cb = l16 * 8;
  uint4 ur = xr4[(unsigned)n * 16u + l16];
  float xr[8];
  unpack8(ur, xr);
  float atv[8];
  {
    const float4* atp = reinterpret_cast<const float4*>(att + cb);
    float4 a0 = atp[0], a1 = atp[1];
    atv[0] = a0.x; atv[1] = a0.y; atv[2] = a0.z; atv[3] = a0.w;
    atv[4] = a1.x; atv[5] = a1.y; atv[6] = a1.z; atv[7] = a1.w;
  }
  float m = -3.0e38f, s = 0.f;
  float acc[8];
#pragma unroll
  for (int k = 0; k < 8; ++k) acc[k] = 0.f;
  for (int i = st; i < en; i += 4) {
    int e = i + g;
    int src = src_s[e < en ? e : en - 1];
    uint4 u = xl4[(unsigned)src * 16u + l16];
    float xv[8];
    unpack8(u, xv);
    float p = 0.f;
#pragma unroll
    for (int k = 0; k < 8; ++k) {
      float sv = xv[k] + xr[k];
      p = fmaf(atv[k], lrelu(sv), p);
    }
    p += __shfl_xor(p, 1);
    p += __shfl_xor(p, 2);
    p += __shfl_xor(p, 4);
    p += __shfl_xor(p, 8);
    if (e >= en) p = -3.0e38f;
    float mn = fmaxf(m, p);
    float al = __expf(m - mn);
    float we = __expf(p - mn);
    s = s * al + we;
#pragma unroll
    for (int k = 0; k < 8; ++k) acc[k] = fmaf(acc[k], al, we * xv[k]);
    m = mn;
  }
#pragma unroll
  for (int d = 16; d < 64; d <<= 1) {
    float mo = __shfl_xor(m, d), so = __shfl_xor(s, d);
    float ao[8];
#pragma unroll
    for (int k = 0; k < 8; ++k) ao[k] = __shfl_xor(acc[k], d);
    float mn = fmaxf(m, mo);
    float e1 = __expf(m - mn), e2 = __expf(mo - mn);
    s = s * e1 + so * e2;
#pragma unroll
    for (int k = 0; k < 8; ++k) acc[k] = acc[k] * e1 + ao[k] * e2;
    m = mn;
  }
  float inv = 1.0f / (s + 1e-16f);
  float v[8];
  float s1 = 0.f, s2 = 0.f;
#pragma unroll
  for (int k = 0; k < 8; ++k) {
    v[k] = fmaf(acc[k], inv, bg[cb + k]);
    s1 += v[k];
    s2 += v[k] * v[k];
  }
#pragma unroll
  for (int mm = 1; mm <= 32; mm <<= 1) { s1 += __shfl_xor(s1, mm); s2 += __shfl_xor(s2, mm); }
  float mu = s1 * (1.0f / 512.0f);               // 4x redundancy over 128 ch
  float var = s2 * (1.0f / 512.0f) - mu * mu;
  float rsd = rsqrtf(var + 1e-5f);
  if (g == 0) {
    float y[8];
#pragma unroll
    for (int k = 0; k < 8; ++k)
      y[k] = elu((v[k] - mu) * rsd * lg[cb + k] + lb[cb + k]);
    float* ep = emb + (size_t)n * 128 + cb;
    *reinterpret_cast<float4*>(ep)     = float4{y[0], y[1], y[2], y[3]};
    *reinterpret_cast<float4*>(ep + 4) = float4{y[4], y[5], y[6], y[7]};
    uint4 o;
    o.x = packbf(y[0], y[1]); o.y = packbf(y[2], y[3]);
    o.z = packbf(y[4], y[5]); o.w = packbf(y[6], y[7]);
    embh4[(unsigned)n * 16u + l16] = o;
  }
}

// ---------------- Fused branch GEMM (N=384) + per-segment LN + relu ----------------
__global__ __launch_bounds__(256) void k_branch(const unsigned short* __restrict__ A,
    const unsigned short* __restrict__ Wp,
    const float* __restrict__ b0, const float* __restrict__ b1s, const float* __restrict__ b2s,
    const float* __restrict__ g0, const float* __restrict__ gb0,
    const float* __restrict__ g1, const float* __restrict__ gb1,
    const float* __restrict__ g2, const float* __restrict__ gb2,
    float* __restrict__ ff) {
  constexpr int KB = 4, TPW = 6;
  __shared__ short As[KB * 64 * 8];
  __shared__ float Cs[16 * 384];
  int row0 = blockIdx.x * 16;
  int t = threadIdx.x, lane = t & 63, w = t >> 6;
  for (int idx = t; idx < KB * 64; idx += 256) {
    int kb = idx >> 6, l = idx & 63;
    const short8v* sp = reinterpret_cast<const short8v*>(
        A + (size_t)(row0 + (l & 15)) * 128 + kb * 32 + (l >> 4) * 8);
    reinterpret_cast<short8v*>(As)[idx] = *sp;
  }
  __syncthreads();
  f32x4 acc[TPW];
#pragma unroll
  for (int j = 0; j < TPW; ++j) acc[j] = f32x4{0.f, 0.f, 0.f, 0.f};
  const short8v* Bp = reinterpret_cast<const short8v*>(Wp);
  for (int kb = 0; kb < KB; ++kb) {
    short8v a = reinterpret_cast<const short8v*>(As)[kb * 64 + lane];
#pragma unroll
    for (int j = 0; j < TPW; ++j) {
      int tile = w * TPW + j;
      short8v b = Bp[(tile * KB + kb) * 64 + lane];
      acc[j] = __builtin_amdgcn_mfma_f32_16x16x32_bf16(a, b, acc[j], 0, 0, 0);
    }
  }
#pragma unroll
  for (int j = 0; j < TPW; ++j) {
    int col = (w * TPW + j) * 16 + (lane & 15);
    int seg = col >> 7, cl = col & 127;
    const float* bp = (seg == 0) ? b0 : (seg == 1) ? b1s : b2s;
    float bs = bp[cl];
#pragma unroll
    for (int r = 0; r < 4; ++r)
      Cs[((lane >> 4) * 4 + r) * 384 + col] = acc[j][r] + bs;
  }
  __syncthreads();
  int row = t >> 4, l16 = t & 15;
#pragma unroll
  for (int seg = 0; seg < 3; ++seg) {
    float v[8];
    float s = 0.f, s2 = 0.f;
    int base = row * 384 + seg * 128 + l16 * 8;
#pragma unroll
    for (int k = 0; k < 8; ++k) { v[k] = Cs[base + k]; s += v[k]; s2 += v[k] * v[k]; }
#pragma unroll
    for (int mm = 1; mm <= 8; mm <<= 1) { s += __shfl_xor(s, mm); s2 += __shfl_xor(s2, mm); }
    float mu = s * (1.0f / 128.0f);
    float var = s2 * (1.0f / 128.0f) - mu * mu;
    float rsd = rsqrtf(var + 1e-5f);
    const float* gp = (seg == 0) ? g0 : (seg == 1) ? g1 : g2;
    const float* bp = (seg == 0) ? gb0 : (seg == 1) ? gb1 : gb2;
    float* op = ff + (size_t)(row0 + row) * 384 + seg * 128 + l16 * 8;
#pragma unroll
    for (int k = 0; k < 8; ++k) {
      int c = l16 * 8 + k;
      op[k] = fmaxf((v[k] - mu) * rsd * gp[c] + bp[c], 0.f);
    }
  }
}

// ---------------- Fused MLP heads (wave per row) ----------------
__global__ __launch_bounds__(256) void k_head_ret(const float* __restrict__ in, int ldi,
    const float* __restrict__ W1, const float* __restrict__ b1,
    const float* __restrict__ W2, const float* __restrict__ b2,
    const float* __restrict__ W3, const float* __restrict__ b3,
    float* __restrict__ out) {
  __shared__ float sh[4][224];
  int wid = threadIdx.x >> 6, lane = threadIdx.x & 63;
  int row = blockIdx.x * 4 + wid;
  const float2* rp = reinterpret_cast<const float2*>(in + (size_t)row * ldi);
  float2 f2 = rp[lane];
  sh[wid][2 * lane] = f2.x;
  sh[wid][2 * lane + 1] = f2.y;
  __syncthreads();
  float a = b1[lane];
#pragma unroll 8
  for (int k = 0; k < 128; ++k) a = fmaf(sh[wid][k], W1[k * 64 + lane], a);
  sh[wid][128 + lane] = fmaxf(a, 0.f);
  __syncthreads();
  if (lane < 32) {
    float a2 = b2[lane];
#pragma unroll 8
    for (int k = 0; k < 64; ++k) a2 = fmaf(sh[wid][128 + k], W2[k * 32 + lane], a2);
    sh[wid][192 + lane] = fmaxf(a2, 0.f);
  }
  __syncthreads();
  if (lane == 0) {
    float a3 = b3[0];
#pragma unroll
    for (int k = 0; k < 32; ++k) a3 = fmaf(sh[wid][192 + k], W3[k], a3);
    out[row] = tanhf(a3) * 0.1f;
  }
}

__global__ __launch_bounds__(256) void k_head_mov(const float* __restrict__ in, int ldi,
    const float* __restrict__ W1, const float* __restrict__ b1,
    const float* __restrict__ W2, const float* __restrict__ b2,
    float* __restrict__ out) {
  __shared__ float sh[4][192];
  int wid = threadIdx.x >> 6, lane = threadIdx.x & 63;
  int row = blockIdx.x * 4 + wid;
  const float2* rp = reinterpret_cast<const float2*>(in + (size_t)row * ldi);
  float2 f2 = rp[lane];
  sh[wid][2 * lane] = f2.x;
  sh[wid][2 * lane + 1] = f2.y;
  __syncthreads();
  float a = b1[lane];
#pragma unroll 8
  for (int k = 0; k < 128; ++k) a = fmaf(sh[wid][k], W1[k * 64 + lane], a);
  sh[wid][128 + lane] = fmaxf(a, 0.f);
  __syncthreads();
  if (lane < 2) {
    float a2 = b2[lane];
#pragma unroll 8
    for (int k = 0; k < 64; ++k) a2 = fmaf(sh[wid][128 + k], W2[k * 2 + lane], a2);
    out[(size_t)row * 2 + lane] = a2;
  }
}

__global__ __launch_bounds__(256) void k_head_rank(const float* __restrict__ in, int ldi,
    const float* __restrict__ W1, const float* __restrict__ b1,
    const float* __restrict__ W2, const float* __restrict__ b2,
    float* __restrict__ out) {
  __shared__ float sh[4][192];
  int wid = threadIdx.x >> 6, lane = threadIdx.x & 63;
  int row = blockIdx.x * 4 + wid;
  const float2* rp = reinterpret_cast<const float2*>(in + (size_t)row * ldi);
  float2 f2 = rp[lane];
  sh[wid][2 * lane] = f2.x;
  sh[wid][2 * lane + 1] = f2.y;
  __syncthreads();
  float a = b1[lane];
#pragma unroll 8
  for (int k = 0; k < 128; ++k) a = fmaf(sh[wid][k], W1[k * 64 + lane], a);
  sh[wid][128 + lane] = fmaxf(a, 0.f);
  __syncthreads();
  if (lane == 0) {
    float a2 = b2[0];
#pragma unroll 8
    for (int k = 0; k < 64; ++k) a2 = fmaf(sh[wid][128 + k], W2[k], a2);
    out[row] = 1.0f / (1.0f + expf(-a2));
  }
}

// ---------------- launch ----------------
extern "C" void kernel_launch(void* const* d_in, const int* in_sizes, int n_in,
                              void* d_out, int out_size, void* d_ws, size_t ws_size,
                              hipStream_t stream) {
  const float* x     = (const float*)d_in[0];
  const int*   ei    = (const int*)  d_in[1];
  const float* fn_g  = (const float*)d_in[2];
  const float* fn_b  = (const float*)d_in[3];
  const float* W_in  = (const float*)d_in[4];
  const float* b_in  = (const float*)d_in[5];
  const float* Wl1   = (const float*)d_in[6];
  const float* bl1   = (const float*)d_in[7];
  const float* Wr1   = (const float*)d_in[8];
  const float* br1   = (const float*)d_in[9];
  const float* att1  = (const float*)d_in[10];
  const float* bg1   = (const float*)d_in[11];
  const float* Wl2   = (const float*)d_in[12];
  const float* bl2   = (const float*)d_in[13];
  const float* Wr2   = (const float*)d_in[14];
  const float* br2   = (const float*)d_in[15];
  const float* att2  = (const float*)d_in[16];
  const float* bg2   = (const float*)d_in[17];
  const float* ln1_g = (const float*)d_in[18];
  const float* ln1_b = (const float*)d_in[19];
  const float* ln2_g = (const float*)d_in[20];
  const float* ln2_b = (const float*)d_in[21];
  const float* Wrf   = (const float*)d_in[22];
  const float* brf   = (const float*)d_in[23];
  const float* rf_g  = (const float*)d_in[24];
  const float* rf_b  = (const float*)d_in[25];
  const float* Wcf   = (const float*)d_in[26];
  const float* bcf   = (const float*)d_in[27];
  const float* cf_g  = (const float*)d_in[28];
  const float* cf_b  = (const float*)d_in[29];
  const float* Wkf   = (const float*)d_in[30];
  const float* bkf   = (const float*)d_in[31];
  const float* kf_g  = (const float*)d_in[32];
  const float* kf_b  = (const float*)d_in[33];
  const float* Wr1h  = (const float*)d_in[34];
  const float* br1h  = (const float*)d_in[35];
  const float* Wr2h  = (const float*)d_in[36];
  const float* br2h  = (const float*)d_in[37];
  const float* Wr3h  = (const float*)d_in[38];
  const float* br3h  = (const float*)d_in[39];
  const float* Wc1h  = (const float*)d_in[40];
  const float* bc1h  = (const float*)d_in[41];
  const float* Wc2h  = (const float*)d_in[42];
  const float* bc2h  = (const float*)d_in[43];
  const float* Wk1h  = (const float*)d_in[44];
  const float* bk1h  = (const float*)d_in[45];
  const float* Wk2h  = (const float*)d_in[46];
  const float* bk2h  = (const float*)d_in[47];

  const int M  = in_sizes[0] / 128;   // 20000
  const int E0 = in_sizes[1] / 2;     // 320000
  const int ET = E0 + M;              // 340000

  char* base = (char*)d_ws;
  size_t off = 0;
  auto carve = [&](size_t bytes) -> char* {
    off = (off + 255) & ~(size_t)255;
    char* p = base + off;
    off += bytes;
    return p;
  };
  const size_t B512 = (size_t)M * 512 * 2;  // bf16
  const size_t B128 = (size_t)M * 128 * 2;
  unsigned short* hnh  = (unsigned short*)carve(B128);
  unsigned short* h0h  = (unsigned short*)carve(B128);
  unsigned short* xl1h = (unsigned short*)carve(B512);
  unsigned short* xr1h = (unsigned short*)carve(B512);
  unsigned short* g1h  = (unsigned short*)carve(B512);
  unsigned short* xl2h = (unsigned short*)carve(B128);
  unsigned short* xr2h = (unsigned short*)carve(B128);
  unsigned short* embh = (unsigned short*)carve(B128);
  int* src_s = (int*)carve((size_t)ET * sizeof(int));
  int* cnt   = (int*)carve((size_t)2 * M * sizeof(int));
  int* cur   = cnt + M;
  int* offs  = (int*)carve((size_t)(M + 1) * sizeof(int));
  unsigned short* Winp = (unsigned short*)carve(128 * 128 * 2);
  unsigned short* Wl1p = (unsigned short*)carve(128 * 512 * 2);
  unsigned short* Wr1p = (unsigned short*)carve(128 * 512 * 2);
  unsigned short* Wl2p = (unsigned short*)carve(512 * 128 * 2);
  unsigned short* Wr2p = (unsigned short*)carve(512 * 128 * 2);
  unsigned short* Wtp  = (unsigned short*)carve(3 * 128 * 128 * 2);
  // ff [M][384] f32 overlays xl1h/xr1h (dead after k_gat1)
  float* ff = (float*)xl1h;
  (void)ws_size; (void)n_in; (void)out_size;

  // CSR by dst
  hipMemsetAsync(cnt, 0, (size_t)2 * M * sizeof(int), stream);
  k_count<<<(ET + 255) / 256, 256, 0, stream>>>(ei, cnt, E0, ET);
  k_scan2<<<1, 1024, 0, stream>>>(cnt, offs, M);
  k_scatter<<<(ET + 255) / 256, 256, 0, stream>>>(ei, offs, cur, src_s, E0, ET);

  // weight packing (one launch)
  k_pack_all<<<256, 256, 0, stream>>>(W_in, Wl1, Wr1, Wl2, Wr2, Wrf, Wcf, Wkf,
                                      Winp, Wl1p, Wr1p, Wl2p, Wr2p,
                                      Wtp, Wtp + 16384, Wtp + 32768);

  // node pipeline (bf16 flow, f32 accum)
  k_ln<128, 0, true><<<M, 128, 0, stream>>>(x, hnh, fn_g, fn_b);
  k_mfma<128, 128, 2, 1, false, true><<<M / 32, 256, 0, stream>>>(hnh, Winp, b_in, nullptr, h0h);
  k_mfma<128, 512, 2, 0, false, true><<<M / 32, 256, 0, stream>>>(h0h, Wl1p, bl1, nullptr, xl1h);
  k_mfma<128, 512, 2, 0, false, true><<<M / 32, 256, 0, stream>>>(h0h, Wr1p, br1, nullptr, xr1h);
  k_gat1<<<M, 256, 0, stream>>>(offs, src_s, (const uint4*)xl1h, (const uint4*)xr1h,
                                att1, bg1, ln1_g, ln1_b, (uint4*)g1h);
  k_mfma<512, 128, 2, 0, false, true><<<M / 32, 256, 0, stream>>>(g1h, Wl2p, bl2, nullptr, xl2h);
  k_mfma<512, 128, 2, 0, false, true><<<M / 32, 256, 0, stream>>>(g1h, Wr2p, br2, nullptr, xr2h);

  float* out_ret  = (float*)d_out;
  float* out_mov  = out_ret + M;
  float* out_rank = out_ret + 3 * M;
  float* emb      = out_ret + 4 * M;
  k_gat2<<<(M + 3) / 4, 256, 0, stream>>>(offs, src_s, (const uint4*)xl2h,
                                          (const uint4*)xr2h, att2, bg2,
                                          ln2_g, ln2_b, emb, (uint4*)embh, M);

  // fused feature branches (GEMM N=384 + LN + relu)
  k_branch<<<M / 16, 256, 0, stream>>>(embh, Wtp, brf, bcf, bkf,
                                       rf_g, rf_b, cf_g, cf_b, kf_g, kf_b, ff);

  // heads (read ff with stride 384, offsets 0/128/256)
  k_head_ret<<<M / 4, 256, 0, stream>>>(ff, 384, Wr1h, br1h, Wr2h, br2h, Wr3h, br3h, out_ret);
  k_head_mov<<<M / 4, 256, 0, stream>>>(ff + 128, 384, Wc1h, bc1h, Wc2h, bc2h, out_mov);
  k_head_rank<<<M / 4, 256, 0, stream>>>(ff + 256, 384, Wk1h, bk1h, Wk2h, bk2h, out_rank);
}

// Round 7
// 337.383 us; speedup vs baseline: 1.0984x; 1.0984x over previous
//
#include <hip/hip_runtime.h>
#include <cmath>

#define DEV __device__ __forceinline__
#define LOG2E 1.44269504088896340736f

typedef __attribute__((ext_vector_type(8))) short short8v;
typedef __attribute__((ext_vector_type(4))) float f32x4;

DEV float lrelu(float v) { return fmaxf(v, 0.2f * v); }
DEV float elu(float v) { return v > 0.f ? v : expm1f(v); }
DEV float plo(unsigned u) { return __uint_as_float(u << 16); }
DEV float phi(unsigned u) { return __uint_as_float(u & 0xffff0000u); }
DEV unsigned short f2bf(float f) {
  unsigned u = __float_as_uint(f);
  unsigned r = (u + 0x7fffu + ((u >> 16) & 1u)) >> 16;
  return (unsigned short)r;
}
DEV unsigned packbf(float a, float b) {
  return (unsigned)f2bf(a) | ((unsigned)f2bf(b) << 16);
}
DEV void unpack8(uint4 u, float* f) {
  f[0] = plo(u.x); f[1] = phi(u.x); f[2] = plo(u.y); f[3] = phi(u.y);
  f[4] = plo(u.z); f[5] = phi(u.z); f[6] = plo(u.w); f[7] = phi(u.w);
}

// ---------------- CSR build ----------------
__global__ void k_count(const int* __restrict__ ei, int* __restrict__ counts,
                        int E0, int ET) {
  int e = blockIdx.x * 256 + threadIdx.x;
  if (e >= ET) return;
  int dst = (e < E0) ? ei[E0 + e] : (e - E0);
  atomicAdd(&counts[dst], 1);
}

__global__ __launch_bounds__(1024) void k_scan2(const int* __restrict__ counts,
                                                int* __restrict__ offs, int n) {
  int t = threadIdx.x;
  int ch = (n + 1023) >> 10;
  int beg = t * ch, end = min(beg + ch, n);
  int loc = 0;
  for (int i = beg; i < end; ++i) loc += counts[i];
  int lane = t & 63, w = t >> 6;
  int v = loc;
#pragma unroll
  for (int m = 1; m < 64; m <<= 1) {
    int u = __shfl_up(v, m);
    if (lane >= m) v += u;
  }
  __shared__ int wsum[16], wpre[16];
  if (lane == 63) wsum[w] = v;
  __syncthreads();
  if (t < 16) {
    int p = 0;
    for (int i = 0; i < t; ++i) p += wsum[i];
    wpre[t] = p;
  }
  __syncthreads();
  int run = wpre[w] + v - loc;
  for (int i = beg; i < end; ++i) { offs[i] = run; run += counts[i]; }
  if (beg < n && end == n) offs[n] = run;
}

__global__ void k_scatter(const int* __restrict__ ei, const int* __restrict__ offs,
                          int* __restrict__ cursor, int* __restrict__ src_s,
                          int E0, int ET) {
  int e = blockIdx.x * 256 + threadIdx.x;
  if (e >= ET) return;
  int src, dst;
  if (e < E0) { src = ei[e]; dst = ei[E0 + e]; }
  else        { src = e - E0; dst = e - E0; }
  int pos = offs[dst] + atomicAdd(&cursor[dst], 1);
  src_s[pos] = src;
}

// ---------------- Weight pack into MFMA B-fragment order ----------------
DEV void pack_one(const float* __restrict__ W, unsigned short* __restrict__ Wp,
                  int K, int N, int idx) {
  if (idx >= K * N) return;
  int j = idx & 7, l = (idx >> 3) & 63, r = idx >> 9;
  int KB = K / 32;
  int tile = r / KB, kb = r - tile * KB;
  int k = kb * 32 + (l >> 4) * 8 + j;
  int col = tile * 16 + (l & 15);
  Wp[idx] = f2bf(W[(size_t)k * N + col]);
}

__global__ void k_pack_all(const float* w0, const float* w1, const float* w2,
                           const float* w3, const float* w4, const float* w5,
                           const float* w6, const float* w7,
                           unsigned short* p0, unsigned short* p1, unsigned short* p2,
                           unsigned short* p3, unsigned short* p4, unsigned short* p5,
                           unsigned short* p6, unsigned short* p7,
                           const float* bl2, const float* br2, float* bcat) {
  int idx = blockIdx.x * 256 + threadIdx.x;
  pack_one(w0, p0, 128, 128, idx);
  pack_one(w1, p1, 128, 512, idx);
  pack_one(w2, p2, 128, 512, idx);
  pack_one(w3, p3, 512, 128, idx);
  pack_one(w4, p4, 512, 128, idx);
  pack_one(w5, p5, 128, 128, idx);
  pack_one(w6, p6, 128, 128, idx);
  pack_one(w7, p7, 128, 128, idx);
  if (idx < 128) bcat[idx] = bl2[idx];
  else if (idx < 256) bcat[idx] = br2[idx - 128];
}

// ---------------- MFMA GEMM: C[M,N] = act(A[M,K](bf16) @ W + bias), RT row-tiles ----------------
template<int K, int N, int RT, int ACT, bool OF32, bool OB16>
__global__ __launch_bounds__(256) void k_mfma(const unsigned short* __restrict__ A,
                                              const unsigned short* __restrict__ Wp,
                                              const float* __restrict__ bias,
                                              float* __restrict__ Cf,
                                              unsigned short* __restrict__ Cb) {
  constexpr int KB = K / 32;
  constexpr int TPW = N / 64;
  __shared__ short As[RT * KB * 64 * 8];
  int row0 = blockIdx.x * (16 * RT);
  int t = threadIdx.x, lane = t & 63, w = t >> 6;
  for (int idx = t; idx < RT * KB * 64; idx += 256) {
    int r = idx / (KB * 64), rem = idx - r * (KB * 64);
    int kb = rem >> 6, l = rem & 63;
    const short8v* sp = reinterpret_cast<const short8v*>(
        A + (size_t)(row0 + r * 16 + (l & 15)) * K + kb * 32 + (l >> 4) * 8);
    reinterpret_cast<short8v*>(As)[idx] = *sp;
  }
  __syncthreads();
  f32x4 acc[RT][TPW];
#pragma unroll
  for (int r = 0; r < RT; ++r)
#pragma unroll
    for (int j = 0; j < TPW; ++j) acc[r][j] = f32x4{0.f, 0.f, 0.f, 0.f};
  const short8v* Bp = reinterpret_cast<const short8v*>(Wp);
  for (int kb = 0; kb < KB; ++kb) {
    short8v a[RT];
#pragma unroll
    for (int r = 0; r < RT; ++r)
      a[r] = reinterpret_cast<const short8v*>(As)[(r * KB + kb) * 64 + lane];
#pragma unroll
    for (int j = 0; j < TPW; ++j) {
      int tile = w * TPW + j;
      short8v b = Bp[(tile * KB + kb) * 64 + lane];
#pragma unroll
      for (int r = 0; r < RT; ++r)
        acc[r][j] = __builtin_amdgcn_mfma_f32_16x16x32_bf16(a[r], b, acc[r][j], 0, 0, 0);
    }
  }
#pragma unroll
  for (int j = 0; j < TPW; ++j) {
    int col = (w * TPW + j) * 16 + (lane & 15);
    float bs = bias[col];
#pragma unroll
    for (int rt = 0; rt < RT; ++rt)
#pragma unroll
      for (int r = 0; r < 4; ++r) {
        int row = row0 + rt * 16 + (lane >> 4) * 4 + r;
        float v = acc[rt][j][r] + bs;
        if (ACT == 1) v = fmaxf(v, 0.f);
        if (OF32) Cf[(size_t)row * N + col] = v;
        if (OB16) Cb[(size_t)row * N + col] = f2bf(v);
      }
  }
}

// ---------------- LayerNorm (x -> bf16) ----------------
template<int C, int ACT, bool OUT16>
__global__ void k_ln(const float* in, void* out, const float* g, const float* b) {
  constexpr int T = (C < 256) ? C : 256;
  constexpr int EPT = C / T;
  int row = blockIdx.x, t = threadIdx.x;
  const float* ip = in + (size_t)row * C;
  float v[EPT];
  float s = 0.f, s2 = 0.f;
#pragma unroll
  for (int e = 0; e < EPT; ++e) { float xv = ip[t + e * T]; v[e] = xv; s += xv; s2 += xv * xv; }
#pragma unroll
  for (int m = 1; m <= 32; m <<= 1) { s += __shfl_xor(s, m); s2 += __shfl_xor(s2, m); }
  __shared__ float w1s[2], w2s[2];
  if (T > 64) {
    if ((t & 63) == 0) { w1s[t >> 6] = s; w2s[t >> 6] = s2; }
    __syncthreads();
    s = w1s[0] + w1s[1];
    s2 = w2s[0] + w2s[1];
  }
  float mu = s * (1.0f / C);
  float var = s2 * (1.0f / C) - mu * mu;
  float rs = rsqrtf(var + 1e-5f);
#pragma unroll
  for (int e = 0; e < EPT; ++e) {
    int c = t + e * T;
    float y = (v[e] - mu) * rs * g[c] + b[c];
    if (ACT == 1) y = fmaxf(y, 0.f);
    if (ACT == 2) y = elu(y);
    if (OUT16) ((unsigned short*)out)[(size_t)row * C + c] = f2bf(y);
    else       ((float*)out)[(size_t)row * C + c] = y;
  }
}

// ---------------- Fused GATv2 layer 1: wave per node, groups = heads ----------------
// Lane l owns channels l*8..l*8+7 (head = l>>4). One edge per wave-iteration.
// Per-head softmax lives in each 16-lane group; defer-max fast path; exp2 domain.
__global__ __launch_bounds__(256) void k_gat1(const int* __restrict__ offs,
                                              const int* __restrict__ src_s,
                                              const uint4* __restrict__ xl4,  // [M][64]
                                              const uint4* __restrict__ xr4,
                                              const float* __restrict__ att,  // [512]
                                              const float* __restrict__ bg,
                                              const float* __restrict__ lg,
                                              const float* __restrict__ lb,
                                              uint4* __restrict__ out4,       // [M][64]
                                              int M) {
  int w = threadIdx.x >> 6, lane = threadIdx.x & 63;
  int n = blockIdx.x * 4 + w;
  if (n >= M) return;
  int st = offs[n], en = offs[n + 1];
  int cb = lane * 8;
  uint4 ur = xr4[(size_t)n * 64 + lane];
  float xr[8];
  unpack8(ur, xr);
  float atv[8];
  {
    const float4* atp = reinterpret_cast<const float4*>(att + cb);
    float4 a0 = atp[0], a1 = atp[1];
    atv[0] = a0.x * LOG2E; atv[1] = a0.y * LOG2E; atv[2] = a0.z * LOG2E; atv[3] = a0.w * LOG2E;
    atv[4] = a1.x * LOG2E; atv[5] = a1.y * LOG2E; atv[6] = a1.z * LOG2E; atv[7] = a1.w * LOG2E;
  }
  float m = -3.0e38f, s = 0.f;
  float acc[8];
#pragma unroll
  for (int k = 0; k < 8; ++k) acc[k] = 0.f;
  uint4 u = xl4[(size_t)src_s[st] * 64 + lane];
  for (int i = st; i < en; ++i) {
    uint4 ucur = u;
    int nx = (i + 1 < en) ? i + 1 : i;
    u = xl4[(size_t)src_s[nx] * 64 + lane];
    float xv[8];
    unpack8(ucur, xv);
    float p = 0.f;
#pragma unroll
    for (int k = 0; k < 8; ++k)
      p = fmaf(atv[k], lrelu(xv[k] + xr[k]), p);
    p += __shfl_xor(p, 1);
    p += __shfl_xor(p, 2);
    p += __shfl_xor(p, 4);
    p += __shfl_xor(p, 8);
    if (__all(p <= m)) {
      float we = exp2f(p - m);
      s += we;
#pragma unroll
      for (int k = 0; k < 8; ++k) acc[k] = fmaf(we, xv[k], acc[k]);
    } else {
      float mn = fmaxf(m, p);
      float al = exp2f(m - mn);
      float we = exp2f(p - mn);
      s = fmaf(s, al, we);
#pragma unroll
      for (int k = 0; k < 8; ++k) acc[k] = fmaf(acc[k], al, we * xv[k]);
      m = mn;
    }
  }
  float inv = 1.0f / (s + 1e-16f);
  float v[8];
  float s1 = 0.f, s2 = 0.f;
#pragma unroll
  for (int k = 0; k < 8; ++k) {
    v[k] = fmaf(acc[k], inv, bg[cb + k]);
    s1 += v[k];
    s2 += v[k] * v[k];
  }
#pragma unroll
  for (int mm = 1; mm <= 32; mm <<= 1) { s1 += __shfl_xor(s1, mm); s2 += __shfl_xor(s2, mm); }
  float mu = s1 * (1.0f / 512.0f);
  float var = s2 * (1.0f / 512.0f) - mu * mu;
  float rsd = rsqrtf(var + 1e-5f);
  float y[8];
#pragma unroll
  for (int k = 0; k < 8; ++k)
    y[k] = elu((v[k] - mu) * rsd * lg[cb + k] + lb[cb + k]);
  uint4 o;
  o.x = packbf(y[0], y[1]); o.y = packbf(y[2], y[3]);
  o.z = packbf(y[4], y[5]); o.w = packbf(y[6], y[7]);
  out4[(size_t)n * 64 + lane] = o;
}

// ---------------- Fused GATv2 layer 2: wave per node, 4 edge-groups ----------------
// xlr4 = [M][32] uint4: cols 0..15 = xl2 (128ch), 16..31 = xr2.
__global__ __launch_bounds__(256) void k_gat2(const int* __restrict__ offs,
                                              const int* __restrict__ src_s,
                                              const uint4* __restrict__ xlr4,
                                              const float* __restrict__ att,  // [128]
                                              const float* __restrict__ bg,
                                              const float* __restrict__ lg,
                                              const float* __restrict__ lb,
                                              float* __restrict__ emb,
                                              uint4* __restrict__ embh4,      // [M][16]
                                              int M) {
  int w = threadIdx.x >> 6, lane = threadIdx.x & 63;
  int n = blockIdx.x * 4 + w;
  if (n >= M) return;
  int st = offs[n], en = offs[n + 1];
  int g = lane >> 4, l16 = lane & 15;
  int cb = l16 * 8;
  uint4 ur = xlr4[(size_t)n * 32 + 16 + l16];
  float xr[8];
  unpack8(ur, xr);
  float atv[8];
  {
    const float4* atp = reinterpret_cast<const float4*>(att + cb);
    float4 a0 = atp[0], a1 = atp[1];
    atv[0] = a0.x * LOG2E; atv[1] = a0.y * LOG2E; atv[2] = a0.z * LOG2E; atv[3] = a0.w * LOG2E;
    atv[4] = a1.x * LOG2E; atv[5] = a1.y * LOG2E; atv[6] = a1.z * LOG2E; atv[7] = a1.w * LOG2E;
  }
  float m = -3.0e38f, s = 0.f;
  float acc[8];
#pragma unroll
  for (int k = 0; k < 8; ++k) acc[k] = 0.f;
  int e0 = st + g;
  uint4 u = xlr4[(size_t)src_s[e0 < en ? e0 : en - 1] * 32 + l16];
  for (int i = st; i < en; i += 4) {
    int e = i + g;
    uint4 ucur = u;
    int e2 = i + 4 + g;
    u = xlr4[(size_t)src_s[e2 < en ? e2 : en - 1] * 32 + l16];
    float xv[8];
    unpack8(ucur, xv);
    float p = 0.f;
#pragma unroll
    for (int k = 0; k < 8; ++k)
      p = fmaf(atv[k], lrelu(xv[k] + xr[k]), p);
    p += __shfl_xor(p, 1);
    p += __shfl_xor(p, 2);
    p += __shfl_xor(p, 4);
    p += __shfl_xor(p, 8);
    if (e >= en) p = -3.0e38f;
    if (__all(p <= m)) {
      float we = exp2f(p - m);
      s += we;
#pragma unroll
      for (int k = 0; k < 8; ++k) acc[k] = fmaf(we, xv[k], acc[k]);
    } else {
      float mn = fmaxf(m, p);
      float al = exp2f(m - mn);
      float we = exp2f(p - mn);
      s = fmaf(s, al, we);
#pragma unroll
      for (int k = 0; k < 8; ++k) acc[k] = fmaf(acc[k], al, we * xv[k]);
      m = mn;
    }
  }
  // merge the 4 edge-groups (butterfly over xor 16, 32), exp2 domain
#pragma unroll
  for (int d = 16; d < 64; d <<= 1) {
    float mo = __shfl_xor(m, d), so = __shfl_xor(s, d);
    float ao[8];
#pragma unroll
    for (int k = 0; k < 8; ++k) ao[k] = __shfl_xor(acc[k], d);
    float mn = fmaxf(m, mo);
    float e1 = exp2f(m - mn), e2m = exp2f(mo - mn);
    s = s * e1 + so * e2m;
#pragma unroll
    for (int k = 0; k < 8; ++k) acc[k] = acc[k] * e1 + ao[k] * e2m;
    m = mn;
  }
  float inv = 1.0f / (s + 1e-16f);
  float v[8];
  float s1 = 0.f, s2 = 0.f;
#pragma unroll
  for (int k = 0; k < 8; ++k) {
    v[k] = fmaf(acc[k], inv, bg[cb + k]);
    s1 += v[k];
    s2 += v[k] * v[k];
  }
#pragma unroll
  for (int mm = 1; mm <= 32; mm <<= 1) { s1 += __shfl_xor(s1, mm); s2 += __shfl_xor(s2, mm); }
  float mu = s1 * (1.0f / 512.0f);               // 128 ch, 4x group redundancy
  float var = s2 * (1.0f / 512.0f) - mu * mu;
  float rsd = rsqrtf(var + 1e-5f);
  if (g == 0) {
    float y[8];
#pragma unroll
    for (int k = 0; k < 8; ++k)
      y[k] = elu((v[k] - mu) * rsd * lg[cb + k] + lb[cb + k]);
    float* ep = emb + (size_t)n * 128 + cb;
    *reinterpret_cast<float4*>(ep)     = float4{y[0], y[1], y[2], y[3]};
    *reinterpret_cast<float4*>(ep + 4) = float4{y[4], y[5], y[6], y[7]};
    uint4 o;
    o.x = packbf(y[0], y[1]); o.y = packbf(y[2], y[3]);
    o.z = packbf(y[4], y[5]); o.w = packbf(y[6], y[7]);
    embh4[(size_t)n * 16 + l16] = o;
  }
}

// ---------------- Fused branch GEMM (N=384) + per-segment LN + relu ----------------
__global__ __launch_bounds__(256) void k_branch(const unsigned short* __restrict__ A,
    const unsigned short* __restrict__ Wp,
    const float* __restrict__ b0, const float* __restrict__ b1s, const float* __restrict__ b2s,
    const float* __restrict__ g0, const float* __restrict__ gb0,
    const float* __restrict__ g1, const float* __restrict__ gb1,
    const float* __restrict__ g2, const float* __restrict__ gb2,
    float* __restrict__ ff) {
  constexpr int KB = 4, TPW = 6;
  __shared__ short As[KB * 64 * 8];
  __shared__ float Cs[16 * 384];
  int row0 = blockIdx.x * 16;
  int t = threadIdx.x, lane = t & 63, w = t >> 6;
  for (int idx = t; idx < KB * 64; idx += 256) {
    int kb = idx >> 6, l = idx & 63;
    const short8v* sp = reinterpret_cast<const short8v*>(
        A + (size_t)(row0 + (l & 15)) * 128 + kb * 32 + (l >> 4) * 8);
    reinterpret_cast<short8v*>(As)[idx] = *sp;
  }
  __syncthreads();
  f32x4 acc[TPW];
#pragma unroll
  for (int j = 0; j < TPW; ++j) acc[j] = f32x4{0.f, 0.f, 0.f, 0.f};
  const short8v* Bp = reinterpret_cast<const short8v*>(Wp);
  for (int kb = 0; kb < KB; ++kb) {
    short8v a = reinterpret_cast<const short8v*>(As)[kb * 64 + lane];
#pragma unroll
    for (int j = 0; j < TPW; ++j) {
      int tile = w * TPW + j;
      short8v b = Bp[(tile * KB + kb) * 64 + lane];
      acc[j] = __builtin_amdgcn_mfma_f32_16x16x32_bf16(a, b, acc[j], 0, 0, 0);
    }
  }
#pragma unroll
  for (int j = 0; j < TPW; ++j) {
    int col = (w * TPW + j) * 16 + (lane & 15);
    int seg = col >> 7, cl = col & 127;
    const float* bp = (seg == 0) ? b0 : (seg == 1) ? b1s : b2s;
    float bs = bp[cl];
#pragma unroll
    for (int r = 0; r < 4; ++r)
      Cs[((lane >> 4) * 4 + r) * 384 + col] = acc[j][r] + bs;
  }
  __syncthreads();
  int row = t >> 4, l16 = t & 15;
#pragma unroll
  for (int seg = 0; seg < 3; ++seg) {
    float v[8];
    float s = 0.f, s2 = 0.f;
    int base = row * 384 + seg * 128 + l16 * 8;
#pragma unroll
    for (int k = 0; k < 8; ++k) { v[k] = Cs[base + k]; s += v[k]; s2 += v[k] * v[k]; }
#pragma unroll
    for (int mm = 1; mm <= 8; mm <<= 1) { s += __shfl_xor(s, mm); s2 += __shfl_xor(s2, mm); }
    float mu = s * (1.0f / 128.0f);
    float var = s2 * (1.0f / 128.0f) - mu * mu;
    float rsd = rsqrtf(var + 1e-5f);
    const float* gp = (seg == 0) ? g0 : (seg == 1) ? g1 : g2;
    const float* bp = (seg == 0) ? gb0 : (seg == 1) ? gb1 : gb2;
    float* op = ff + (size_t)(row0 + row) * 384 + seg * 128 + l16 * 8;
#pragma unroll
    for (int k = 0; k < 8; ++k) {
      int c = l16 * 8 + k;
      op[k] = fmaxf((v[k] - mu) * rsd * gp[c] + bp[c], 0.f);
    }
  }
}

// ---------------- All 3 MLP heads in one kernel (wave per row; type per block) ----------------
__global__ __launch_bounds__(256) void k_heads(const float* __restrict__ ff, int nb,
    const float* __restrict__ Wr1h, const float* __restrict__ br1h,
    const float* __restrict__ Wr2h, const float* __restrict__ br2h,
    const float* __restrict__ Wr3h, const float* __restrict__ br3h,
    const float* __restrict__ Wc1h, const float* __restrict__ bc1h,
    const float* __restrict__ Wc2h, const float* __restrict__ bc2h,
    const float* __restrict__ Wk1h, const float* __restrict__ bk1h,
    const float* __restrict__ Wk2h, const float* __restrict__ bk2h,
    float* __restrict__ out_ret, float* __restrict__ out_mov,
    float* __restrict__ out_rank) {
  int type = blockIdx.x / nb;
  int b = blockIdx.x - type * nb;
  __shared__ float sh[4][224];
  int wid = threadIdx.x >> 6, lane = threadIdx.x & 63;
  int row = b * 4 + wid;
  const float* in = ff + (type == 0 ? 0 : (type == 1 ? 128 : 256));
  const float2* rp = reinterpret_cast<const float2*>(in + (size_t)row * 384);
  float2 f2 = rp[lane];
  sh[wid][2 * lane] = f2.x;
  sh[wid][2 * lane + 1] = f2.y;
  __syncthreads();
  const float* W1 = (type == 0) ? Wr1h : (type == 1) ? Wc1h : Wk1h;
  const float* b1 = (type == 0) ? br1h : (type == 1) ? bc1h : bk1h;
  float a = b1[lane];
#pragma unroll 8
  for (int k = 0; k < 128; ++k) a = fmaf(sh[wid][k], W1[k * 64 + lane], a);
  sh[wid][128 + lane] = fmaxf(a, 0.f);
  __syncthreads();
  if (type == 0) {
    if (lane < 32) {
      float a2 = br2h[lane];
#pragma unroll 8
      for (int k = 0; k < 64; ++k) a2 = fmaf(sh[wid][128 + k], Wr2h[k * 32 + lane], a2);
      sh[wid][192 + lane] = fmaxf(a2, 0.f);
    }
    __syncthreads();
    if (lane == 0) {
      float a3 = br3h[0];
#pragma unroll
      for (int k = 0; k < 32; ++k) a3 = fmaf(sh[wid][192 + k], Wr3h[k], a3);
      out_ret[row] = tanhf(a3) * 0.1f;
    }
  } else if (type == 1) {
    if (lane < 2) {
      float a2 = bc2h[lane];
#pragma unroll 8
      for (int k = 0; k < 64; ++k) a2 = fmaf(sh[wid][128 + k], Wc2h[k * 2 + lane], a2);
      out_mov[(size_t)row * 2 + lane] = a2;
    }
  } else {
    if (lane == 0) {
      float a2 = bk2h[0];
#pragma unroll 8
      for (int k = 0; k < 64; ++k) a2 = fmaf(sh[wid][128 + k], Wk2h[k], a2);
      out_rank[row] = 1.0f / (1.0f + expf(-a2));
    }
  }
}

// ---------------- launch ----------------
extern "C" void kernel_launch(void* const* d_in, const int* in_sizes, int n_in,
                              void* d_out, int out_size, void* d_ws, size_t ws_size,
                              hipStream_t stream) {
  const float* x     = (const float*)d_in[0];
  const int*   ei    = (const int*)  d_in[1];
  const float* fn_g  = (const float*)d_in[2];
  const float* fn_b  = (const float*)d_in[3];
  const float* W_in  = (const float*)d_in[4];
  const float* b_in  = (const float*)d_in[5];
  const float* Wl1   = (const float*)d_in[6];
  const float* bl1   = (const float*)d_in[7];
  const float* Wr1   = (const float*)d_in[8];
  const float* br1   = (const float*)d_in[9];
  const float* att1  = (const float*)d_in[10];
  const float* bg1   = (const float*)d_in[11];
  const float* Wl2   = (const float*)d_in[12];
  const float* bl2   = (const float*)d_in[13];
  const float* Wr2   = (const float*)d_in[14];
  const float* br2   = (const float*)d_in[15];
  const float* att2  = (const float*)d_in[16];
  const float* bg2   = (const float*)d_in[17];
  const float* ln1_g = (const float*)d_in[18];
  const float* ln1_b = (const float*)d_in[19];
  const float* ln2_g = (const float*)d_in[20];
  const float* ln2_b = (const float*)d_in[21];
  const float* Wrf   = (const float*)d_in[22];
  const float* brf   = (const float*)d_in[23];
  const float* rf_g  = (const float*)d_in[24];
  const float* rf_b  = (const float*)d_in[25];
  const float* Wcf   = (const float*)d_in[26];
  const float* bcf   = (const float*)d_in[27];
  const float* cf_g  = (const float*)d_in[28];
  const float* cf_b  = (const float*)d_in[29];
  const float* Wkf   = (const float*)d_in[30];
  const float* bkf   = (const float*)d_in[31];
  const float* kf_g  = (const float*)d_in[32];
  const float* kf_b  = (const float*)d_in[33];
  const float* Wr1h  = (const float*)d_in[34];
  const float* br1h  = (const float*)d_in[35];
  const float* Wr2h  = (const float*)d_in[36];
  const float* br2h  = (const float*)d_in[37];
  const float* Wr3h  = (const float*)d_in[38];
  const float* br3h  = (const float*)d_in[39];
  const float* Wc1h  = (const float*)d_in[40];
  const float* bc1h  = (const float*)d_in[41];
  const float* Wc2h  = (const float*)d_in[42];
  const float* bc2h  = (const float*)d_in[43];
  const float* Wk1h  = (const float*)d_in[44];
  const float* bk1h  = (const float*)d_in[45];
  const float* Wk2h  = (const float*)d_in[46];
  const float* bk2h  = (const float*)d_in[47];

  const int M  = in_sizes[0] / 128;   // 20000
  const int E0 = in_sizes[1] / 2;     // 320000
  const int ET = E0 + M;              // 340000

  char* base = (char*)d_ws;
  size_t off = 0;
  auto carve = [&](size_t bytes) -> char* {
    off = (off + 255) & ~(size_t)255;
    char* p = base + off;
    off += bytes;
    return p;
  };
  const size_t B512 = (size_t)M * 512 * 2;  // bf16
  const size_t B256 = (size_t)M * 256 * 2;
  const size_t B128 = (size_t)M * 128 * 2;
  unsigned short* hnh   = (unsigned short*)carve(B128);
  unsigned short* h0h   = (unsigned short*)carve(B128);
  unsigned short* xl1h  = (unsigned short*)carve(B512);
  unsigned short* xr1h  = (unsigned short*)carve(B512);
  unsigned short* g1h   = (unsigned short*)carve(B512);
  unsigned short* xlr2h = (unsigned short*)carve(B256);   // [M][256]: xl2 | xr2
  unsigned short* embh  = (unsigned short*)carve(B128);
  int* src_s = (int*)carve((size_t)(ET + 8) * sizeof(int));
  int* cnt   = (int*)carve((size_t)2 * M * sizeof(int));
  int* cur   = cnt + M;
  int* offs  = (int*)carve((size_t)(M + 1) * sizeof(int));
  unsigned short* Winp = (unsigned short*)carve(128 * 128 * 2);
  unsigned short* Wl1p = (unsigned short*)carve(128 * 512 * 2);
  unsigned short* Wr1p = (unsigned short*)carve(128 * 512 * 2);
  unsigned short* Wl2p = (unsigned short*)carve(512 * 128 * 2);  // + Wr2p contiguous
  unsigned short* Wr2p = (unsigned short*)carve(512 * 128 * 2);
  unsigned short* Wtp  = (unsigned short*)carve(3 * 128 * 128 * 2);
  float* bcat = (float*)carve(256 * sizeof(float));
  // ff [M][384] f32 overlays xl1h/xr1h (dead after k_gat1)
  float* ff = (float*)xl1h;
  (void)ws_size; (void)n_in; (void)out_size; (void)Wr2p;

  // CSR by dst
  hipMemsetAsync(cnt, 0, (size_t)2 * M * sizeof(int), stream);
  k_count<<<(ET + 255) / 256, 256, 0, stream>>>(ei, cnt, E0, ET);
  k_scan2<<<1, 1024, 0, stream>>>(cnt, offs, M);
  k_scatter<<<(ET + 255) / 256, 256, 0, stream>>>(ei, offs, cur, src_s, E0, ET);

  // weight packing (one launch); Wl2p/Wr2p adjacent -> merged [512,256] packed buffer
  k_pack_all<<<256, 256, 0, stream>>>(W_in, Wl1, Wr1, Wl2, Wr2, Wrf, Wcf, Wkf,
                                      Winp, Wl1p, Wr1p, Wl2p, Wr2p,
                                      Wtp, Wtp + 16384, Wtp + 32768,
                                      bl2, br2, bcat);

  // node pipeline (bf16 flow, f32 accum)
  k_ln<128, 0, true><<<M, 128, 0, stream>>>(x, hnh, fn_g, fn_b);
  k_mfma<128, 128, 2, 1, false, true><<<M / 32, 256, 0, stream>>>(hnh, Winp, b_in, nullptr, h0h);
  k_mfma<128, 512, 2, 0, false, true><<<M / 32, 256, 0, stream>>>(h0h, Wl1p, bl1, nullptr, xl1h);
  k_mfma<128, 512, 2, 0, false, true><<<M / 32, 256, 0, stream>>>(h0h, Wr1p, br1, nullptr, xr1h);
  k_gat1<<<(M + 3) / 4, 256, 0, stream>>>(offs, src_s, (const uint4*)xl1h, (const uint4*)xr1h,
                                          att1, bg1, ln1_g, ln1_b, (uint4*)g1h, M);
  k_mfma<512, 256, 2, 0, false, true><<<M / 32, 256, 0, stream>>>(g1h, Wl2p, bcat, nullptr, xlr2h);

  float* out_ret  = (float*)d_out;
  float* out_mov  = out_ret + M;
  float* out_rank = out_ret + 3 * M;
  float* emb      = out_ret + 4 * M;
  k_gat2<<<(M + 3) / 4, 256, 0, stream>>>(offs, src_s, (const uint4*)xlr2h,
                                          att2, bg2, ln2_g, ln2_b, emb, (uint4*)embh, M);

  // fused feature branches (GEMM N=384 + LN + relu)
  k_branch<<<M / 16, 256, 0, stream>>>(embh, Wtp, brf, bcf, bkf,
                                       rf_g, rf_b, cf_g, cf_b, kf_g, kf_b, ff);

  // all heads in one launch
  int nb = M / 4;
  k_heads<<<3 * nb, 256, 0, stream>>>(ff, nb,
                                      Wr1h, br1h, Wr2h, br2h, Wr3h, br3h,
                                      Wc1h, bc1h, Wc2h, bc2h,
                                      Wk1h, bk1h, Wk2h, bk2h,
                                      out_ret, out_mov, out_rank);
}

// Round 8
// 285.363 us; speedup vs baseline: 1.2987x; 1.1823x over previous
//
#include <hip/hip_runtime.h>
#include <cmath>

#define DEV __device__ __forceinline__
#define LOG2E 1.44269504088896340736f

typedef __attribute__((ext_vector_type(8))) short short8v;
typedef __attribute__((ext_vector_type(4))) float f32x4;

DEV float lrelu(float v) { return fmaxf(v, 0.2f * v); }
DEV float elu(float v) { return v > 0.f ? v : expm1f(v); }
DEV float plo(unsigned u) { return __uint_as_float(u << 16); }
DEV float phi(unsigned u) { return __uint_as_float(u & 0xffff0000u); }
DEV unsigned short f2bf(float f) {
  unsigned u = __float_as_uint(f);
  unsigned r = (u + 0x7fffu + ((u >> 16) & 1u)) >> 16;
  return (unsigned short)r;
}
DEV unsigned packbf(float a, float b) {
  return (unsigned)f2bf(a) | ((unsigned)f2bf(b) << 16);
}
DEV void unpack8(uint4 u, float* f) {
  f[0] = plo(u.x); f[1] = phi(u.x); f[2] = plo(u.y); f[3] = phi(u.y);
  f[4] = plo(u.z); f[5] = phi(u.z); f[6] = plo(u.w); f[7] = phi(u.w);
}

// ---------------- CSR build ----------------
__global__ void k_count(const int* __restrict__ ei, int* __restrict__ counts,
                        int E0, int ET) {
  int e = blockIdx.x * 256 + threadIdx.x;
  if (e >= ET) return;
  int dst = (e < E0) ? ei[E0 + e] : (e - E0);
  atomicAdd(&counts[dst], 1);
}

__global__ __launch_bounds__(1024) void k_scan2(const int* __restrict__ counts,
                                                int* __restrict__ offs, int n) {
  int t = threadIdx.x;
  int ch = (n + 1023) >> 10;
  int beg = t * ch, end = min(beg + ch, n);
  int loc = 0;
  for (int i = beg; i < end; ++i) loc += counts[i];
  int lane = t & 63, w = t >> 6;
  int v = loc;
#pragma unroll
  for (int m = 1; m < 64; m <<= 1) {
    int u = __shfl_up(v, m);
    if (lane >= m) v += u;
  }
  __shared__ int wsum[16], wpre[16];
  if (lane == 63) wsum[w] = v;
  __syncthreads();
  if (t < 16) {
    int p = 0;
    for (int i = 0; i < t; ++i) p += wsum[i];
    wpre[t] = p;
  }
  __syncthreads();
  int run = wpre[w] + v - loc;
  for (int i = beg; i < end; ++i) { offs[i] = run; run += counts[i]; }
  if (beg < n && end == n) offs[n] = run;
}

__global__ void k_scatter(const int* __restrict__ ei, const int* __restrict__ offs,
                          int* __restrict__ cursor, int* __restrict__ src_s,
                          int E0, int ET) {
  int e = blockIdx.x * 256 + threadIdx.x;
  if (e >= ET) return;
  int src, dst;
  if (e < E0) { src = ei[e]; dst = ei[E0 + e]; }
  else        { src = e - E0; dst = e - E0; }
  int pos = offs[dst] + atomicAdd(&cursor[dst], 1);
  src_s[pos] = src;
}

// ---------------- Weight pack into MFMA B-fragment order ----------------
DEV void pack_one(const float* __restrict__ W, unsigned short* __restrict__ Wp,
                  int K, int N, int idx) {
  if (idx >= K * N) return;
  int j = idx & 7, l = (idx >> 3) & 63, r = idx >> 9;
  int KB = K / 32;
  int tile = r / KB, kb = r - tile * KB;
  int k = kb * 32 + (l >> 4) * 8 + j;
  int col = tile * 16 + (l & 15);
  Wp[idx] = f2bf(W[(size_t)k * N + col]);
}

__global__ void k_pack_all(const float* w0, const float* w1, const float* w2,
                           const float* w3, const float* w4, const float* w5,
                           const float* w6, const float* w7,
                           unsigned short* p0, unsigned short* p1, unsigned short* p2,
                           unsigned short* p3, unsigned short* p4, unsigned short* p5,
                           unsigned short* p6, unsigned short* p7,
                           const float* bl2, const float* br2, float* bcat) {
  int idx = blockIdx.x * 256 + threadIdx.x;
  pack_one(w0, p0, 128, 128, idx);
  pack_one(w1, p1, 128, 512, idx);
  pack_one(w2, p2, 128, 512, idx);
  pack_one(w3, p3, 512, 128, idx);
  pack_one(w4, p4, 512, 128, idx);
  pack_one(w5, p5, 128, 128, idx);
  pack_one(w6, p6, 128, 128, idx);
  pack_one(w7, p7, 128, 128, idx);
  if (idx < 128) bcat[idx] = bl2[idx];
  else if (idx < 256) bcat[idx] = br2[idx - 128];
}

// ---------------- Head weight pack (block-diagonal) ----------------
DEV float bd1_val(const float* Wr, const float* Wc, const float* Wk, int k, int col) {
  int blk = col >> 6;
  if ((k >> 7) != blk) return 0.f;
  const float* W = (blk == 0) ? Wr : (blk == 1) ? Wc : Wk;
  return W[(k & 127) * 64 + (col & 63)];
}
DEV float bd2_val(const float* Wr2, const float* Wc2, const float* Wk2, int k, int col) {
  if (col < 32) return (k < 64) ? Wr2[k * 32 + col] : 0.f;
  if (col < 34) return (k >= 64 && k < 128) ? Wc2[(k - 64) * 2 + (col - 32)] : 0.f;
  if (col == 34) return (k >= 128) ? Wk2[k - 128] : 0.f;
  return 0.f;
}

__global__ void k_pack_heads(const float* Wr1, const float* Wc1, const float* Wk1,
                             const float* Wr2, const float* Wc2, const float* Wk2,
                             const float* br1, const float* bc1, const float* bk1,
                             const float* br2, const float* bc2, const float* bk2,
                             unsigned short* P1, unsigned short* P2,
                             float* bh1, float* bh2) {
  int idx = blockIdx.x * 256 + threadIdx.x;
  if (idx < 384 * 192) {
    int j = idx & 7, l = (idx >> 3) & 63, r = idx >> 9;
    const int KB = 12;
    int tile = r / KB, kb = r - tile * KB;
    int k = kb * 32 + (l >> 4) * 8 + j;
    int col = tile * 16 + (l & 15);
    P1[idx] = f2bf(bd1_val(Wr1, Wc1, Wk1, k, col));
  }
  if (idx < 192 * 64) {
    int j = idx & 7, l = (idx >> 3) & 63, r = idx >> 9;
    const int KB = 6;
    int tile = r / KB, kb = r - tile * KB;
    int k = kb * 32 + (l >> 4) * 8 + j;
    int col = tile * 16 + (l & 15);
    P2[idx] = f2bf(bd2_val(Wr2, Wc2, Wk2, k, col));
  }
  if (idx < 192) bh1[idx] = (idx < 64) ? br1[idx] : (idx < 128) ? bc1[idx - 64] : bk1[idx - 128];
  if (idx < 64)
    bh2[idx] = (idx < 32) ? br2[idx] : (idx < 34) ? bc2[idx - 32] : (idx == 34) ? bk2[0] : 0.f;
}

// ---------------- MFMA GEMM: C[M,N] = act(A[M,K](bf16) @ W + bias), RT row-tiles ----------------
template<int K, int N, int RT, int ACT, bool OF32, bool OB16>
__global__ __launch_bounds__(256) void k_mfma(const unsigned short* __restrict__ A,
                                              const unsigned short* __restrict__ Wp,
                                              const float* __restrict__ bias,
                                              float* __restrict__ Cf,
                                              unsigned short* __restrict__ Cb) {
  constexpr int KB = K / 32;
  constexpr int TPW = N / 64;
  __shared__ short As[RT * KB * 64 * 8];
  int row0 = blockIdx.x * (16 * RT);
  int t = threadIdx.x, lane = t & 63, w = t >> 6;
  for (int idx = t; idx < RT * KB * 64; idx += 256) {
    int r = idx / (KB * 64), rem = idx - r * (KB * 64);
    int kb = rem >> 6, l = rem & 63;
    const short8v* sp = reinterpret_cast<const short8v*>(
        A + (size_t)(row0 + r * 16 + (l & 15)) * K + kb * 32 + (l >> 4) * 8);
    reinterpret_cast<short8v*>(As)[idx] = *sp;
  }
  __syncthreads();
  f32x4 acc[RT][TPW];
#pragma unroll
  for (int r = 0; r < RT; ++r)
#pragma unroll
    for (int j = 0; j < TPW; ++j) acc[r][j] = f32x4{0.f, 0.f, 0.f, 0.f};
  const short8v* Bp = reinterpret_cast<const short8v*>(Wp);
  for (int kb = 0; kb < KB; ++kb) {
    short8v a[RT];
#pragma unroll
    for (int r = 0; r < RT; ++r)
      a[r] = reinterpret_cast<const short8v*>(As)[(r * KB + kb) * 64 + lane];
#pragma unroll
    for (int j = 0; j < TPW; ++j) {
      int tile = w * TPW + j;
      short8v b = Bp[(tile * KB + kb) * 64 + lane];
#pragma unroll
      for (int r = 0; r < RT; ++r)
        acc[r][j] = __builtin_amdgcn_mfma_f32_16x16x32_bf16(a[r], b, acc[r][j], 0, 0, 0);
    }
  }
#pragma unroll
  for (int j = 0; j < TPW; ++j) {
    int col = (w * TPW + j) * 16 + (lane & 15);
    float bs = bias[col];
#pragma unroll
    for (int rt = 0; rt < RT; ++rt)
#pragma unroll
      for (int r = 0; r < 4; ++r) {
        int row = row0 + rt * 16 + (lane >> 4) * 4 + r;
        float v = acc[rt][j][r] + bs;
        if (ACT == 1) v = fmaxf(v, 0.f);
        if (OF32) Cf[(size_t)row * N + col] = v;
        if (OB16) Cb[(size_t)row * N + col] = f2bf(v);
      }
  }
}

// ---------------- LayerNorm (x -> bf16) ----------------
template<int C, int ACT, bool OUT16>
__global__ void k_ln(const float* in, void* out, const float* g, const float* b) {
  constexpr int T = (C < 256) ? C : 256;
  constexpr int EPT = C / T;
  int row = blockIdx.x, t = threadIdx.x;
  const float* ip = in + (size_t)row * C;
  float v[EPT];
  float s = 0.f, s2 = 0.f;
#pragma unroll
  for (int e = 0; e < EPT; ++e) { float xv = ip[t + e * T]; v[e] = xv; s += xv; s2 += xv * xv; }
#pragma unroll
  for (int m = 1; m <= 32; m <<= 1) { s += __shfl_xor(s, m); s2 += __shfl_xor(s2, m); }
  __shared__ float w1s[2], w2s[2];
  if (T > 64) {
    if ((t & 63) == 0) { w1s[t >> 6] = s; w2s[t >> 6] = s2; }
    __syncthreads();
    s = w1s[0] + w1s[1];
    s2 = w2s[0] + w2s[1];
  }
  float mu = s * (1.0f / C);
  float var = s2 * (1.0f / C) - mu * mu;
  float rs = rsqrtf(var + 1e-5f);
#pragma unroll
  for (int e = 0; e < EPT; ++e) {
    int c = t + e * T;
    float y = (v[e] - mu) * rs * g[c] + b[c];
    if (ACT == 1) y = fmaxf(y, 0.f);
    if (ACT == 2) y = elu(y);
    if (OUT16) ((unsigned short*)out)[(size_t)row * C + c] = f2bf(y);
    else       ((float*)out)[(size_t)row * C + c] = y;
  }
}

// ---------------- Fused GATv2 layer 1: wave per node, groups = heads ----------------
__global__ __launch_bounds__(256) void k_gat1(const int* __restrict__ offs,
                                              const int* __restrict__ src_s,
                                              const uint4* __restrict__ xl4,  // [M][64]
                                              const uint4* __restrict__ xr4,
                                              const float* __restrict__ att,  // [512]
                                              const float* __restrict__ bg,
                                              const float* __restrict__ lg,
                                              const float* __restrict__ lb,
                                              uint4* __restrict__ out4,       // [M][64]
                                              int M) {
  int w = threadIdx.x >> 6, lane = threadIdx.x & 63;
  int n = blockIdx.x * 4 + w;
  if (n >= M) return;
  int st = offs[n], en = offs[n + 1];
  int cb = lane * 8;
  uint4 ur = xr4[(size_t)n * 64 + lane];
  float xr[8];
  unpack8(ur, xr);
  float atv[8];
  {
    const float4* atp = reinterpret_cast<const float4*>(att + cb);
    float4 a0 = atp[0], a1 = atp[1];
    atv[0] = a0.x * LOG2E; atv[1] = a0.y * LOG2E; atv[2] = a0.z * LOG2E; atv[3] = a0.w * LOG2E;
    atv[4] = a1.x * LOG2E; atv[5] = a1.y * LOG2E; atv[6] = a1.z * LOG2E; atv[7] = a1.w * LOG2E;
  }
  float m = -3.0e38f, s = 0.f;
  float acc[8];
#pragma unroll
  for (int k = 0; k < 8; ++k) acc[k] = 0.f;
  uint4 u = xl4[(size_t)src_s[st] * 64 + lane];
  for (int i = st; i < en; ++i) {
    uint4 ucur = u;
    int nx = (i + 1 < en) ? i + 1 : i;
    u = xl4[(size_t)src_s[nx] * 64 + lane];
    float xv[8];
    unpack8(ucur, xv);
    float p = 0.f;
#pragma unroll
    for (int k = 0; k < 8; ++k)
      p = fmaf(atv[k], lrelu(xv[k] + xr[k]), p);
    p += __shfl_xor(p, 1);
    p += __shfl_xor(p, 2);
    p += __shfl_xor(p, 4);
    p += __shfl_xor(p, 8);
    if (__all(p <= m)) {
      float we = exp2f(p - m);
      s += we;
#pragma unroll
      for (int k = 0; k < 8; ++k) acc[k] = fmaf(we, xv[k], acc[k]);
    } else {
      float mn = fmaxf(m, p);
      float al = exp2f(m - mn);
      float we = exp2f(p - mn);
      s = fmaf(s, al, we);
#pragma unroll
      for (int k = 0; k < 8; ++k) acc[k] = fmaf(acc[k], al, we * xv[k]);
      m = mn;
    }
  }
  float inv = 1.0f / (s + 1e-16f);
  float v[8];
  float s1 = 0.f, s2 = 0.f;
#pragma unroll
  for (int k = 0; k < 8; ++k) {
    v[k] = fmaf(acc[k], inv, bg[cb + k]);
    s1 += v[k];
    s2 += v[k] * v[k];
  }
#pragma unroll
  for (int mm = 1; mm <= 32; mm <<= 1) { s1 += __shfl_xor(s1, mm); s2 += __shfl_xor(s2, mm); }
  float mu = s1 * (1.0f / 512.0f);
  float var = s2 * (1.0f / 512.0f) - mu * mu;
  float rsd = rsqrtf(var + 1e-5f);
  float y[8];
#pragma unroll
  for (int k = 0; k < 8; ++k)
    y[k] = elu((v[k] - mu) * rsd * lg[cb + k] + lb[cb + k]);
  uint4 o;
  o.x = packbf(y[0], y[1]); o.y = packbf(y[2], y[3]);
  o.z = packbf(y[4], y[5]); o.w = packbf(y[6], y[7]);
  out4[(size_t)n * 64 + lane] = o;
}

// ---------------- Fused GATv2 layer 2: wave per node, 4 edge-groups ----------------
__global__ __launch_bounds__(256) void k_gat2(const int* __restrict__ offs,
                                              const int* __restrict__ src_s,
                                              const uint4* __restrict__ xlr4,  // [M][32]
                                              const float* __restrict__ att,   // [128]
                                              const float* __restrict__ bg,
                                              const float* __restrict__ lg,
                                              const float* __restrict__ lb,
                                              float* __restrict__ emb,
                                              uint4* __restrict__ embh4,       // [M][16]
                                              int M) {
  int w = threadIdx.x >> 6, lane = threadIdx.x & 63;
  int n = blockIdx.x * 4 + w;
  if (n >= M) return;
  int st = offs[n], en = offs[n + 1];
  int g = lane >> 4, l16 = lane & 15;
  int cb = l16 * 8;
  uint4 ur = xlr4[(size_t)n * 32 + 16 + l16];
  float xr[8];
  unpack8(ur, xr);
  float atv[8];
  {
    const float4* atp = reinterpret_cast<const float4*>(att + cb);
    float4 a0 = atp[0], a1 = atp[1];
    atv[0] = a0.x * LOG2E; atv[1] = a0.y * LOG2E; atv[2] = a0.z * LOG2E; atv[3] = a0.w * LOG2E;
    atv[4] = a1.x * LOG2E; atv[5] = a1.y * LOG2E; atv[6] = a1.z * LOG2E; atv[7] = a1.w * LOG2E;
  }
  float m = -3.0e38f, s = 0.f;
  float acc[8];
#pragma unroll
  for (int k = 0; k < 8; ++k) acc[k] = 0.f;
  int e0 = st + g;
  uint4 u = xlr4[(size_t)src_s[e0 < en ? e0 : en - 1] * 32 + l16];
  for (int i = st; i < en; i += 4) {
    int e = i + g;
    uint4 ucur = u;
    int e2 = i + 4 + g;
    u = xlr4[(size_t)src_s[e2 < en ? e2 : en - 1] * 32 + l16];
    float xv[8];
    unpack8(ucur, xv);
    float p = 0.f;
#pragma unroll
    for (int k = 0; k < 8; ++k)
      p = fmaf(atv[k], lrelu(xv[k] + xr[k]), p);
    p += __shfl_xor(p, 1);
    p += __shfl_xor(p, 2);
    p += __shfl_xor(p, 4);
    p += __shfl_xor(p, 8);
    if (e >= en) p = -3.0e38f;
    if (__all(p <= m)) {
      float we = exp2f(p - m);
      s += we;
#pragma unroll
      for (int k = 0; k < 8; ++k) acc[k] = fmaf(we, xv[k], acc[k]);
    } else {
      float mn = fmaxf(m, p);
      float al = exp2f(m - mn);
      float we = exp2f(p - mn);
      s = fmaf(s, al, we);
#pragma unroll
      for (int k = 0; k < 8; ++k) acc[k] = fmaf(acc[k], al, we * xv[k]);
      m = mn;
    }
  }
#pragma unroll
  for (int d = 16; d < 64; d <<= 1) {
    float mo = __shfl_xor(m, d), so = __shfl_xor(s, d);
    float ao[8];
#pragma unroll
    for (int k = 0; k < 8; ++k) ao[k] = __shfl_xor(acc[k], d);
    float mn = fmaxf(m, mo);
    float e1 = exp2f(m - mn), e2m = exp2f(mo - mn);
    s = s * e1 + so * e2m;
#pragma unroll
    for (int k = 0; k < 8; ++k) acc[k] = acc[k] * e1 + ao[k] * e2m;
    m = mn;
  }
  float inv = 1.0f / (s + 1e-16f);
  float v[8];
  float s1 = 0.f, s2 = 0.f;
#pragma unroll
  for (int k = 0; k < 8; ++k) {
    v[k] = fmaf(acc[k], inv, bg[cb + k]);
    s1 += v[k];
    s2 += v[k] * v[k];
  }
#pragma unroll
  for (int mm = 1; mm <= 32; mm <<= 1) { s1 += __shfl_xor(s1, mm); s2 += __shfl_xor(s2, mm); }
  float mu = s1 * (1.0f / 512.0f);
  float var = s2 * (1.0f / 512.0f) - mu * mu;
  float rsd = rsqrtf(var + 1e-5f);
  if (g == 0) {
    float y[8];
#pragma unroll
    for (int k = 0; k < 8; ++k)
      y[k] = elu((v[k] - mu) * rsd * lg[cb + k] + lb[cb + k]);
    float* ep = emb + (size_t)n * 128 + cb;
    *reinterpret_cast<float4*>(ep)     = float4{y[0], y[1], y[2], y[3]};
    *reinterpret_cast<float4*>(ep + 4) = float4{y[4], y[5], y[6], y[7]};
    uint4 o;
    o.x = packbf(y[0], y[1]); o.y = packbf(y[2], y[3]);
    o.z = packbf(y[4], y[5]); o.w = packbf(y[6], y[7]);
    embh4[(size_t)n * 16 + l16] = o;
  }
}

// ---------------- Fused branch GEMM (N=384) + per-segment LN + relu -> bf16 ----------------
__global__ __launch_bounds__(256) void k_branch(const unsigned short* __restrict__ A,
    const unsigned short* __restrict__ Wp,
    const float* __restrict__ b0, const float* __restrict__ b1s, const float* __restrict__ b2s,
    const float* __restrict__ g0, const float* __restrict__ gb0,
    const float* __restrict__ g1, const float* __restrict__ gb1,
    const float* __restrict__ g2, const float* __restrict__ gb2,
    unsigned* __restrict__ ffh) {   // [M][192] bf16-pairs
  constexpr int KB = 4, TPW = 6;
  __shared__ short As[KB * 64 * 8];
  __shared__ float Cs[16 * 384];
  int row0 = blockIdx.x * 16;
  int t = threadIdx.x, lane = t & 63, w = t >> 6;
  for (int idx = t; idx < KB * 64; idx += 256) {
    int kb = idx >> 6, l = idx & 63;
    const short8v* sp = reinterpret_cast<const short8v*>(
        A + (size_t)(row0 + (l & 15)) * 128 + kb * 32 + (l >> 4) * 8);
    reinterpret_cast<short8v*>(As)[idx] = *sp;
  }
  __syncthreads();
  f32x4 acc[TPW];
#pragma unroll
  for (int j = 0; j < TPW; ++j) acc[j] = f32x4{0.f, 0.f, 0.f, 0.f};
  const short8v* Bp = reinterpret_cast<const short8v*>(Wp);
  for (int kb = 0; kb < KB; ++kb) {
    short8v a = reinterpret_cast<const short8v*>(As)[kb * 64 + lane];
#pragma unroll
    for (int j = 0; j < TPW; ++j) {
      int tile = w * TPW + j;
      short8v b = Bp[(tile * KB + kb) * 64 + lane];
      acc[j] = __builtin_amdgcn_mfma_f32_16x16x32_bf16(a, b, acc[j], 0, 0, 0);
    }
  }
#pragma unroll
  for (int j = 0; j < TPW; ++j) {
    int col = (w * TPW + j) * 16 + (lane & 15);
    int seg = col >> 7, cl = col & 127;
    const float* bp = (seg == 0) ? b0 : (seg == 1) ? b1s : b2s;
    float bs = bp[cl];
#pragma unroll
    for (int r = 0; r < 4; ++r)
      Cs[((lane >> 4) * 4 + r) * 384 + col] = acc[j][r] + bs;
  }
  __syncthreads();
  int row = t >> 4, l16 = t & 15;
#pragma unroll
  for (int seg = 0; seg < 3; ++seg) {
    float v[8];
    float s = 0.f, s2 = 0.f;
    int base = row * 384 + seg * 128 + l16 * 8;
#pragma unroll
    for (int k = 0; k < 8; ++k) { v[k] = Cs[base + k]; s += v[k]; s2 += v[k] * v[k]; }
#pragma unroll
    for (int mm = 1; mm <= 8; mm <<= 1) { s += __shfl_xor(s, mm); s2 += __shfl_xor(s2, mm); }
    float mu = s * (1.0f / 128.0f);
    float var = s2 * (1.0f / 128.0f) - mu * mu;
    float rsd = rsqrtf(var + 1e-5f);
    const float* gp = (seg == 0) ? g0 : (seg == 1) ? g1 : g2;
    const float* bp = (seg == 0) ? gb0 : (seg == 1) ? gb1 : gb2;
    unsigned* op = ffh + (size_t)(row0 + row) * 192 + seg * 64 + l16 * 4;
    float y[8];
#pragma unroll
    for (int k = 0; k < 8; ++k) {
      int c = l16 * 8 + k;
      y[k] = fmaxf((v[k] - mu) * rsd * gp[c] + bp[c], 0.f);
    }
    op[0] = packbf(y[0], y[1]); op[1] = packbf(y[2], y[3]);
    op[2] = packbf(y[4], y[5]); op[3] = packbf(y[6], y[7]);
  }
}

// ---------------- Head tail: ret/mov/rank from tmp[M][64] ----------------
__global__ void k_tail(const float* __restrict__ tmp,
                       const float* __restrict__ Wr3, const float* __restrict__ br3,
                       float* __restrict__ out_ret, float* __restrict__ out_mov,
                       float* __restrict__ out_rank, int M) {
  int row = blockIdx.x * 256 + threadIdx.x;
  if (row >= M) return;
  const float4* tp = reinterpret_cast<const float4*>(tmp + (size_t)row * 64);
  float4 v[9];
#pragma unroll
  for (int q = 0; q < 9; ++q) v[q] = tp[q];
  const float* tv = reinterpret_cast<const float*>(v);
  float a3 = br3[0];
#pragma unroll
  for (int k = 0; k < 32; ++k) a3 = fmaf(fmaxf(tv[k], 0.f), Wr3[k], a3);
  out_ret[row] = tanhf(a3) * 0.1f;
  out_mov[2 * row]     = tv[32];
  out_mov[2 * row + 1] = tv[33];
  out_rank[row] = 1.0f / (1.0f + expf(-tv[34]));
}

// ---------------- launch ----------------
extern "C" void kernel_launch(void* const* d_in, const int* in_sizes, int n_in,
                              void* d_out, int out_size, void* d_ws, size_t ws_size,
                              hipStream_t stream) {
  const float* x     = (const float*)d_in[0];
  const int*   ei    = (const int*)  d_in[1];
  const float* fn_g  = (const float*)d_in[2];
  const float* fn_b  = (const float*)d_in[3];
  const float* W_in  = (const float*)d_in[4];
  const float* b_in  = (const float*)d_in[5];
  const float* Wl1   = (const float*)d_in[6];
  const float* bl1   = (const float*)d_in[7];
  const float* Wr1   = (const float*)d_in[8];
  const float* br1   = (const float*)d_in[9];
  const float* att1  = (const float*)d_in[10];
  const float* bg1   = (const float*)d_in[11];
  const float* Wl2   = (const float*)d_in[12];
  const float* bl2   = (const float*)d_in[13];
  const float* Wr2   = (const float*)d_in[14];
  const float* br2   = (const float*)d_in[15];
  const float* att2  = (const float*)d_in[16];
  const float* bg2   = (const float*)d_in[17];
  const float* ln1_g = (const float*)d_in[18];
  const float* ln1_b = (const float*)d_in[19];
  const float* ln2_g = (const float*)d_in[20];
  const float* ln2_b = (const float*)d_in[21];
  const float* Wrf   = (const float*)d_in[22];
  const float* brf   = (const float*)d_in[23];
  const float* rf_g  = (const float*)d_in[24];
  const float* rf_b  = (const float*)d_in[25];
  const float* Wcf   = (const float*)d_in[26];
  const float* bcf   = (const float*)d_in[27];
  const float* cf_g  = (const float*)d_in[28];
  const float* cf_b  = (const float*)d_in[29];
  const float* Wkf   = (const float*)d_in[30];
  const float* bkf   = (const float*)d_in[31];
  const float* kf_g  = (const float*)d_in[32];
  const float* kf_b  = (const float*)d_in[33];
  const float* Wr1h  = (const float*)d_in[34];
  const float* br1h  = (const float*)d_in[35];
  const float* Wr2h  = (const float*)d_in[36];
  const float* br2h  = (const float*)d_in[37];
  const float* Wr3h  = (const float*)d_in[38];
  const float* br3h  = (const float*)d_in[39];
  const float* Wc1h  = (const float*)d_in[40];
  const float* bc1h  = (const float*)d_in[41];
  const float* Wc2h  = (const float*)d_in[42];
  const float* bc2h  = (const float*)d_in[43];
  const float* Wk1h  = (const float*)d_in[44];
  const float* bk1h  = (const float*)d_in[45];
  const float* Wk2h  = (const float*)d_in[46];
  const float* bk2h  = (const float*)d_in[47];

  const int M  = in_sizes[0] / 128;   // 20000
  const int E0 = in_sizes[1] / 2;     // 320000
  const int ET = E0 + M;              // 340000

  char* base = (char*)d_ws;
  size_t off = 0;
  auto carve = [&](size_t bytes) -> char* {
    off = (off + 255) & ~(size_t)255;
    char* p = base + off;
    off += bytes;
    return p;
  };
  const size_t B512 = (size_t)M * 512 * 2;  // bf16
  const size_t B256 = (size_t)M * 256 * 2;
  const size_t B128 = (size_t)M * 128 * 2;
  unsigned short* hnh   = (unsigned short*)carve(B128);
  unsigned short* h0h   = (unsigned short*)carve(B128);
  unsigned short* xl1h  = (unsigned short*)carve(B512);
  unsigned short* xr1h  = (unsigned short*)carve(B512);
  unsigned short* g1h   = (unsigned short*)carve(B512);
  unsigned short* xlr2h = (unsigned short*)carve(B256);   // [M][256]: xl2 | xr2
  unsigned short* embh  = (unsigned short*)carve(B128);
  int* src_s = (int*)carve((size_t)(ET + 8) * sizeof(int));
  int* cnt   = (int*)carve((size_t)2 * M * sizeof(int));
  int* cur   = cnt + M;
  int* offs  = (int*)carve((size_t)(M + 1) * sizeof(int));
  unsigned short* Winp = (unsigned short*)carve(128 * 128 * 2);
  unsigned short* Wl1p = (unsigned short*)carve(128 * 512 * 2);
  unsigned short* Wr1p = (unsigned short*)carve(128 * 512 * 2);
  unsigned short* Wl2p = (unsigned short*)carve(512 * 128 * 2);  // + Wr2p contiguous
  unsigned short* Wr2p = (unsigned short*)carve(512 * 128 * 2);
  unsigned short* Wtp  = (unsigned short*)carve(3 * 128 * 128 * 2);
  unsigned short* Wh1p = (unsigned short*)carve(384 * 192 * 2);
  unsigned short* Wh2p = (unsigned short*)carve(192 * 64 * 2);
  float* bcat = (float*)carve(256 * sizeof(float));
  float* bh1  = (float*)carve(192 * sizeof(float));
  float* bh2  = (float*)carve(64 * sizeof(float));
  // overlays (regions dead after k_gat1 / k_gat2):
  unsigned* ffh = (unsigned*)xl1h;                 // [M][96] pairs = [M][192] bf16
  unsigned short* h1h = xr1h;                      // [M][192] bf16
  float* tmp = (float*)g1h;                        // [M][64] f32
  (void)ws_size; (void)n_in; (void)out_size; (void)Wr2p;

  // CSR by dst
  hipMemsetAsync(cnt, 0, (size_t)2 * M * sizeof(int), stream);
  k_count<<<(ET + 255) / 256, 256, 0, stream>>>(ei, cnt, E0, ET);
  k_scan2<<<1, 1024, 0, stream>>>(cnt, offs, M);
  k_scatter<<<(ET + 255) / 256, 256, 0, stream>>>(ei, offs, cur, src_s, E0, ET);

  // weight packing
  k_pack_all<<<256, 256, 0, stream>>>(W_in, Wl1, Wr1, Wl2, Wr2, Wrf, Wcf, Wkf,
                                      Winp, Wl1p, Wr1p, Wl2p, Wr2p,
                                      Wtp, Wtp + 16384, Wtp + 32768,
                                      bl2, br2, bcat);
  k_pack_heads<<<288, 256, 0, stream>>>(Wr1h, Wc1h, Wk1h, Wr2h, Wc2h, Wk2h,
                                        br1h, bc1h, bk1h, br2h, bc2h, bk2h,
                                        Wh1p, Wh2p, bh1, bh2);

  // node pipeline (bf16 flow, f32 accum)
  k_ln<128, 0, true><<<M, 128, 0, stream>>>(x, hnh, fn_g, fn_b);
  k_mfma<128, 128, 2, 1, false, true><<<M / 32, 256, 0, stream>>>(hnh, Winp, b_in, nullptr, h0h);
  k_mfma<128, 512, 2, 0, false, true><<<M / 32, 256, 0, stream>>>(h0h, Wl1p, bl1, nullptr, xl1h);
  k_mfma<128, 512, 2, 0, false, true><<<M / 32, 256, 0, stream>>>(h0h, Wr1p, br1, nullptr, xr1h);
  k_gat1<<<(M + 3) / 4, 256, 0, stream>>>(offs, src_s, (const uint4*)xl1h, (const uint4*)xr1h,
                                          att1, bg1, ln1_g, ln1_b, (uint4*)g1h, M);
  k_mfma<512, 256, 2, 0, false, true><<<M / 32, 256, 0, stream>>>(g1h, Wl2p, bcat, nullptr, xlr2h);

  float* out_ret  = (float*)d_out;
  float* out_mov  = out_ret + M;
  float* out_rank = out_ret + 3 * M;
  float* emb      = out_ret + 4 * M;
  k_gat2<<<(M + 3) / 4, 256, 0, stream>>>(offs, src_s, (const uint4*)xlr2h,
                                          att2, bg2, ln2_g, ln2_b, emb, (uint4*)embh, M);

  // fused feature branches (GEMM N=384 + LN + relu) -> bf16 ffh [M][192*2ch]
  k_branch<<<M / 16, 256, 0, stream>>>(embh, Wtp, brf, bcf, bkf,
                                       rf_g, rf_b, cf_g, cf_b, kf_g, kf_b, ffh);

  // heads: two block-diagonal MFMA GEMMs + scalar tail
  k_mfma<384, 192, 2, 1, false, true><<<M / 32, 256, 0, stream>>>(
      (const unsigned short*)ffh, Wh1p, bh1, nullptr, h1h);
  k_mfma<192, 64, 2, 0, true, false><<<M / 32, 256, 0, stream>>>(
      h1h, Wh2p, bh2, tmp, nullptr);
  k_tail<<<(M + 255) / 256, 256, 0, stream>>>(tmp, Wr3h, br3h,
                                              out_ret, out_mov, out_rank, M);
}